// Round 1
// baseline (928.371 us; speedup 1.0000x reference)
//
#include <hip/hip_runtime.h>
#include <math.h>

#define PAIRS 512
#define MAXN 192

// ---------------- offsets: exclusive prefix sums of len_s / len_t ----------------
__global__ void offsets_kernel(const int* __restrict__ ls, const int* __restrict__ lt,
                               int* __restrict__ off) {
    __shared__ int a[PAIRS], b[PAIRS];
    int t = threadIdx.x;
    a[t] = ls[t];
    b[t] = lt[t];
    __syncthreads();
    int sa = 0, sb = 0;
    for (int q = 0; q < t; q++) { sa += a[q]; sb += b[q]; }
    off[t] = sa;
    off[PAIRS + t] = sb;
}

// ---------------- segment_sum via atomics: agg[dst][k] += feat[src][k] ----------------
template <int F>
__global__ __launch_bounds__(256) void scatter_kernel(const float* __restrict__ feat,
                                                      const int* __restrict__ ei,
                                                      float* __restrict__ agg, int E) {
    long long tid = (long long)blockIdx.x * 256 + threadIdx.x;
    if (tid >= (long long)E * F) return;
    int e = (int)(tid / F);
    int k = (int)(tid % F);
    int s = ei[e];        // ei[0] row: source
    int d = ei[E + e];    // ei[1] row: destination (segment id)
    atomicAdd(&agg[(size_t)d * F + k], feat[(size_t)s * F + k]);
}

// ---------------- h_out = relu(agg @ Wrel + b + hin @ Wroot) ----------------
template <int KIN>
__global__ __launch_bounds__(256) void lin_kernel(const float* __restrict__ agg,
                                                  const float* __restrict__ hin,
                                                  const float* __restrict__ Wrel,
                                                  const float* __restrict__ brel,
                                                  const float* __restrict__ Wroot,
                                                  float* __restrict__ hout, int N) {
    __shared__ float wR[KIN * 64];
    __shared__ float wO[KIN * 64];
    __shared__ float bb[64];
    int tid = threadIdx.x;
    for (int t = tid; t < KIN * 64; t += 256) { wR[t] = Wrel[t]; wO[t] = Wroot[t]; }
    if (tid < 64) bb[tid] = brel[tid];
    __syncthreads();
    int o = tid & 63, wg = tid >> 6;
    int base = blockIdx.x * 32 + wg * 8;
    for (int rr = 0; rr < 8; rr++) {
        int row = base + rr;
        if (row >= N) return;  // uniform within the wave
        float acc = bb[o];
        const float* ar = agg + (size_t)row * KIN;
        const float* hr = hin + (size_t)row * KIN;
#pragma unroll
        for (int k = 0; k < KIN; k++) acc = fmaf(ar[k], wR[k * 64 + o], acc);
#pragma unroll
        for (int k = 0; k < KIN; k++) acc = fmaf(hr[k], wO[k * 64 + o], acc);
        hout[(size_t)row * 64 + o] = fmaxf(acc, 0.f);
    }
}

// ---------------- emb = normalize(concat(x,h1,h2) @ W_e + b_e) ----------------
__global__ __launch_bounds__(256) void emb_kernel(const float* __restrict__ x,
                                                  const float* __restrict__ h1,
                                                  const float* __restrict__ h2,
                                                  const float* __restrict__ We,
                                                  const float* __restrict__ be,
                                                  float* __restrict__ emb, int N) {
    __shared__ float w[160 * 64];  // 40 KB
    __shared__ float bb[64];
    int tid = threadIdx.x;
    for (int t = tid; t < 160 * 64; t += 256) w[t] = We[t];
    if (tid < 64) bb[tid] = be[tid];
    __syncthreads();
    int o = tid & 63, wg = tid >> 6;
    int base = blockIdx.x * 32 + wg * 8;
    for (int rr = 0; rr < 8; rr++) {
        int row = base + rr;
        if (row >= N) return;  // uniform within the wave
        float acc = bb[o];
        const float* xr = x + (size_t)row * 32;
#pragma unroll
        for (int k = 0; k < 32; k++) acc = fmaf(xr[k], w[k * 64 + o], acc);
        const float* h1r = h1 + (size_t)row * 64;
#pragma unroll
        for (int k = 0; k < 64; k++) acc = fmaf(h1r[k], w[(32 + k) * 64 + o], acc);
        const float* h2r = h2 + (size_t)row * 64;
#pragma unroll
        for (int k = 0; k < 64; k++) acc = fmaf(h2r[k], w[(96 + k) * 64 + o], acc);
        // L2 normalize across the wave (64 lanes == 64 outputs of this row)
        float ss = acc * acc;
#pragma unroll
        for (int d = 32; d > 0; d >>= 1) ss += __shfl_xor(ss, d, 64);
        float nrm = fmaxf(sqrtf(ss), 1e-12f);
        emb[(size_t)row * 64 + o] = acc / nrm;
    }
}

// ---------------- cost: per (pair, 96-row half), cdist + masking ----------------
__global__ __launch_bounds__(256) void cost_kernel(const float* __restrict__ embS,
                                                   const float* __restrict__ embT,
                                                   const float* __restrict__ vraw,
                                                   const int* __restrict__ lenS,
                                                   const int* __restrict__ lenT,
                                                   const int* __restrict__ off,
                                                   float* __restrict__ cost, int Ns) {
    int p = blockIdx.x >> 1;
    int half = blockIdx.x & 1;
    __shared__ float sS[96 * 65];    // stride 65: bank = (row+k)%32, conflict-free
    __shared__ float sT[192 * 65];
    __shared__ float sqS[96];
    __shared__ float sqT[192];
    __shared__ __align__(16) float virt[64];
    int tid = threadIdx.x;
    int n = lenS[p], m = lenT[p];
    int offs = off[p], offt = off[PAIRS + p];

    if (tid < 64) {
        float v = vraw[tid];
        float ss = v * v;
#pragma unroll
        for (int d = 32; d > 0; d >>= 1) ss += __shfl_xor(ss, d, 64);
        virt[tid] = v / fmaxf(sqrtf(ss), 1e-12f);
    }
    __syncthreads();

    // stage S rows (this half's 96 rows, clipped gather like the reference)
    for (int t = tid; t < 96 * 16; t += 256) {
        int r = t >> 4, q = t & 15;
        int gi = offs + half * 96 + r;
        if (gi > Ns - 1) gi = Ns - 1;
        float4 vv = ((const float4*)embS)[(size_t)gi * 16 + q];
        sS[r * 65 + q * 4 + 0] = vv.x;
        sS[r * 65 + q * 4 + 1] = vv.y;
        sS[r * 65 + q * 4 + 2] = vv.z;
        sS[r * 65 + q * 4 + 3] = vv.w;
    }
    // stage T rows: j<m from emb_t, else normalized virtual
    for (int t = tid; t < 192 * 16; t += 256) {
        int j = t >> 4, q = t & 15;
        float4 vv;
        if (j < m) vv = ((const float4*)embT)[(size_t)(offt + j) * 16 + q];
        else       vv = ((const float4*)virt)[q];
        sT[j * 65 + q * 4 + 0] = vv.x;
        sT[j * 65 + q * 4 + 1] = vv.y;
        sT[j * 65 + q * 4 + 2] = vv.z;
        sT[j * 65 + q * 4 + 3] = vv.w;
    }
    __syncthreads();

    for (int r = tid; r < 96; r += 256) {
        float s = 0.f;
#pragma unroll
        for (int k = 0; k < 64; k++) { float a = sS[r * 65 + k]; s = fmaf(a, a, s); }
        sqS[r] = s;
    }
    for (int j = tid; j < 192; j += 256) {
        float s = 0.f;
#pragma unroll
        for (int k = 0; k < 64; k++) { float a = sT[j * 65 + k]; s = fmaf(a, a, s); }
        sqT[j] = s;
    }
    __syncthreads();

    // 6x12 register tile per thread: 16 i-groups x 16 j-groups
    int ti = tid & 15, tj = tid >> 4;
    int ibase = ti * 6, jbase = tj * 12;
    float acc[6][12];
#pragma unroll
    for (int r = 0; r < 6; r++)
#pragma unroll
        for (int c = 0; c < 12; c++) acc[r][c] = 0.f;

    for (int k = 0; k < 64; k++) {
        float sv[6], tv[12];
#pragma unroll
        for (int r = 0; r < 6; r++) sv[r] = sS[(ibase + r) * 65 + k];
#pragma unroll
        for (int c = 0; c < 12; c++) tv[c] = sT[(jbase + c) * 65 + k];
#pragma unroll
        for (int r = 0; r < 6; r++)
#pragma unroll
            for (int c = 0; c < 12; c++) acc[r][c] = fmaf(sv[r], tv[c], acc[r][c]);
    }

    int i0 = half * 96;
#pragma unroll
    for (int r = 0; r < 6; r++) {
        int i = i0 + ibase + r;
        bool rv = i < n;
        float sqi = sqS[ibase + r];
        float* orow = cost + ((size_t)p * MAXN + i) * MAXN + jbase;
        float tmp[12];
#pragma unroll
        for (int c = 0; c < 12; c++) {
            int j = jbase + c;
            float cd = sqrtf(fmaxf(sqi + sqT[j] - 2.f * acc[r][c], 1e-12f));
            bool cv = j < n;
            tmp[c] = (rv && cv) ? cd : ((!rv && !cv) ? 0.f : 1000.f);
        }
#pragma unroll
        for (int q = 0; q < 3; q++)
            ((float4*)orow)[q] = make_float4(tmp[4 * q], tmp[4 * q + 1], tmp[4 * q + 2], tmp[4 * q + 3]);
    }
}

// ---------------- Sinkhorn (K resident in LDS) + gamma + geds2 ----------------
__global__ __launch_bounds__(256) void sinkhorn_kernel(const float* __restrict__ cost,
                                                       float* __restrict__ gamma,
                                                       float* __restrict__ geds2,
                                                       const int* __restrict__ lenS,
                                                       const int* __restrict__ lenT) {
    int p = blockIdx.x;
    __shared__ float K[MAXN * 193];  // stride 193: bank=(i+j)%32, both matvecs conflict-free
    __shared__ float u[MAXN];
    __shared__ float v[MAXN];
    __shared__ float red[4];
    int tid = threadIdx.x;
    const float* cp = cost + (size_t)p * MAXN * MAXN;

    for (int t = tid; t < MAXN * MAXN; t += 256) {
        int i = t / MAXN, j = t - i * MAXN;
        K[i * 193 + j] = expf(-10.f * cp[t]);  // cost=1000 -> exact 0; cost=0 -> exact 1
    }
    for (int t = tid; t < MAXN; t += 256) u[t] = 1.f / 192.f;

    for (int it = 0; it < 8; it++) {
        __syncthreads();
        if (tid < MAXN) {  // v_j = 1 / sum_i K_ij u_i
            float s = 0.f;
            for (int i = 0; i < MAXN; i++) s = fmaf(K[i * 193 + tid], u[i], s);
            v[tid] = 1.f / s;
        }
        __syncthreads();
        if (tid < MAXN) {  // u_i = 1 / sum_j K_ij v_j
            float s = 0.f;
            for (int j = 0; j < MAXN; j++) s = fmaf(K[tid * 193 + j], v[j], s);
            u[tid] = 1.f / s;
        }
    }
    __syncthreads();

    float acc = 0.f;
    float* gp = gamma + (size_t)p * MAXN * MAXN;
    for (int t = tid; t < MAXN * MAXN; t += 256) {
        int i = t / MAXN, j = t - i * MAXN;
        float Kij = K[i * 193 + j];
        float g = u[i] * Kij * v[j];
        gp[t] = g;
        // cost = -0.1*log(K) (exact 0 in pad block; K==0 => gamma==0, skip)
        if (Kij > 0.f) acc = fmaf(g, -0.1f * logf(Kij), acc);
    }
#pragma unroll
    for (int d = 32; d > 0; d >>= 1) acc += __shfl_xor(acc, d, 64);
    int lane = tid & 63, wv = tid >> 6;
    if (lane == 0) red[wv] = acc;
    __syncthreads();
    if (tid == 0) {
        float g = red[0] + red[1] + red[2] + red[3];
        geds2[p] = g / (float)(lenS[p] + lenT[p]);
    }
}

extern "C" void kernel_launch(void* const* d_in, const int* in_sizes, int n_in,
                              void* d_out, int out_size, void* d_ws, size_t ws_size,
                              hipStream_t stream) {
    const float* x_s     = (const float*)d_in[0];
    const float* x_t     = (const float*)d_in[1];
    const float* W_rel0  = (const float*)d_in[2];
    const float* b_rel0  = (const float*)d_in[3];
    const float* W_root0 = (const float*)d_in[4];
    const float* W_rel1  = (const float*)d_in[5];
    const float* b_rel1  = (const float*)d_in[6];
    const float* W_root1 = (const float*)d_in[7];
    const float* W_e     = (const float*)d_in[8];
    const float* b_e     = (const float*)d_in[9];
    const float* virt    = (const float*)d_in[10];
    const int*   ei_s    = (const int*)d_in[11];
    const int*   ei_t    = (const int*)d_in[12];
    const int*   len_s   = (const int*)d_in[13];
    const int*   len_t   = (const int*)d_in[14];

    int Ns = in_sizes[0] / 32;
    int Nt = in_sizes[1] / 32;
    int Es = in_sizes[11] / 2;
    int Et = in_sizes[12] / 2;

    // workspace layout (all 16B aligned)
    int*   off  = (int*)d_ws;                          // 1024 ints
    float* base = (float*)((char*)d_ws + 4096);
    float* aggS = base;                                // Ns*64 (also final emb_s)
    float* h1S  = aggS + (size_t)Ns * 64;
    float* h2S  = h1S + (size_t)Ns * 64;
    float* aggT = h2S + (size_t)Ns * 64;               // Nt*64 (also final emb_t)
    float* h1T  = aggT + (size_t)Nt * 64;
    float* h2T  = h1T + (size_t)Nt * 64;

    float* out_gamma = (float*)d_out;
    float* out_cost  = out_gamma + (size_t)PAIRS * MAXN * MAXN;
    float* out_geds  = out_cost + (size_t)PAIRS * MAXN * MAXN;

    offsets_kernel<<<1, PAIRS, 0, stream>>>(len_s, len_t, off);

    // ---- source graph GNN ----
    hipMemsetAsync(aggS, 0, (size_t)Ns * 32 * 4, stream);
    scatter_kernel<32><<<(int)(((long long)Es * 32 + 255) / 256), 256, 0, stream>>>(x_s, ei_s, aggS, Es);
    lin_kernel<32><<<(Ns + 31) / 32, 256, 0, stream>>>(aggS, x_s, W_rel0, b_rel0, W_root0, h1S, Ns);
    hipMemsetAsync(aggS, 0, (size_t)Ns * 64 * 4, stream);
    scatter_kernel<64><<<(int)(((long long)Es * 64 + 255) / 256), 256, 0, stream>>>(h1S, ei_s, aggS, Es);
    lin_kernel<64><<<(Ns + 31) / 32, 256, 0, stream>>>(aggS, h1S, W_rel1, b_rel1, W_root1, h2S, Ns);
    emb_kernel<<<(Ns + 31) / 32, 256, 0, stream>>>(x_s, h1S, h2S, W_e, b_e, aggS, Ns);  // emb_s -> aggS

    // ---- target graph GNN ----
    hipMemsetAsync(aggT, 0, (size_t)Nt * 32 * 4, stream);
    scatter_kernel<32><<<(int)(((long long)Et * 32 + 255) / 256), 256, 0, stream>>>(x_t, ei_t, aggT, Et);
    lin_kernel<32><<<(Nt + 31) / 32, 256, 0, stream>>>(aggT, x_t, W_rel0, b_rel0, W_root0, h1T, Nt);
    hipMemsetAsync(aggT, 0, (size_t)Nt * 64 * 4, stream);
    scatter_kernel<64><<<(int)(((long long)Et * 64 + 255) / 256), 256, 0, stream>>>(h1T, ei_t, aggT, Et);
    lin_kernel<64><<<(Nt + 31) / 32, 256, 0, stream>>>(aggT, h1T, W_rel1, b_rel1, W_root1, h2T, Nt);
    emb_kernel<<<(Nt + 31) / 32, 256, 0, stream>>>(x_t, h1T, h2T, W_e, b_e, aggT, Nt);  // emb_t -> aggT

    // ---- cost + sinkhorn ----
    cost_kernel<<<PAIRS * 2, 256, 0, stream>>>(aggS, aggT, virt, len_s, len_t, off, out_cost, Ns);
    sinkhorn_kernel<<<PAIRS, 256, 0, stream>>>(out_cost, out_gamma, out_geds, len_s, len_t);
}

// Round 2
// 904.840 us; speedup vs baseline: 1.0260x; 1.0260x over previous
//
#include <hip/hip_runtime.h>
#include <math.h>

#define PAIRS 512
#define MAXN 192

// ---------------- offsets: exclusive prefix sums of len_s / len_t ----------------
__global__ void offsets_kernel(const int* __restrict__ ls, const int* __restrict__ lt,
                               int* __restrict__ off) {
    __shared__ int a[PAIRS], b[PAIRS];
    int t = threadIdx.x;
    a[t] = ls[t];
    b[t] = lt[t];
    __syncthreads();
    int sa = 0, sb = 0;
    for (int q = 0; q < t; q++) { sa += a[q]; sb += b[q]; }
    off[t] = sa;
    off[PAIRS + t] = sb;
}

// ================= CSR build: count -> scan -> fill =================
__global__ __launch_bounds__(256) void count_kernel(const int* __restrict__ ei,
                                                    int* __restrict__ cnt, int E) {
    int e = blockIdx.x * 256 + threadIdx.x;
    if (e < E) atomicAdd(&cnt[ei[E + e]], 1);
}

// in-place exclusive scan, 1024 ints per block; blockSums[b] = block total
__global__ __launch_bounds__(256) void scan1_kernel(int* __restrict__ data,
                                                    int* __restrict__ blockSums, int N) {
    __shared__ int sc[256];
    int t = threadIdx.x;
    int base = blockIdx.x * 1024;
    int v[4];
    int s = 0;
#pragma unroll
    for (int q = 0; q < 4; q++) {
        int i = base + t * 4 + q;
        v[q] = (i < N) ? data[i] : 0;
        s += v[q];
    }
    sc[t] = s;
    __syncthreads();
    for (int d = 1; d < 256; d <<= 1) {
        int x = (t >= d) ? sc[t - d] : 0;
        __syncthreads();
        sc[t] += x;
        __syncthreads();
    }
    int excl = sc[t] - s;
#pragma unroll
    for (int q = 0; q < 4; q++) {
        int i = base + t * 4 + q;
        if (i < N) { data[i] = excl; excl += v[q]; }
    }
    if (t == 255) blockSums[blockIdx.x] = sc[255];
}

__global__ void scan2_kernel(int* __restrict__ blockSums, int B) {
    if (threadIdx.x == 0) {
        int run = 0;
        for (int b = 0; b < B; b++) { int t = blockSums[b]; blockSums[b] = run; run += t; }
    }
}

__global__ __launch_bounds__(256) void scan3_kernel(int* __restrict__ data,
                                                    const int* __restrict__ blockSums,
                                                    int* __restrict__ cursor, int N) {
    int i = blockIdx.x * 256 + threadIdx.x;
    if (i < N) {
        int v = data[i] + blockSums[i >> 10];
        data[i] = v;
        cursor[i] = v;
    }
}

__global__ __launch_bounds__(256) void fill_kernel(const int* __restrict__ ei,
                                                   int* __restrict__ cursor,
                                                   int* __restrict__ src, int E) {
    int e = blockIdx.x * 256 + threadIdx.x;
    if (e < E) {
        int p = atomicAdd(&cursor[ei[E + e]], 1);
        src[p] = ei[e];
    }
}
// after fill: cursor[r] == row-end, data/rowstart[r] == row-begin

// ================= gather aggregation (replaces scatter atomics) =================
__global__ __launch_bounds__(256) void gather64_kernel(const float* __restrict__ feat,
                                                       const int* __restrict__ rs,
                                                       const int* __restrict__ re,
                                                       const int* __restrict__ src,
                                                       float* __restrict__ agg, int N) {
    int w = (blockIdx.x * 256 + threadIdx.x) >> 6;  // wave id = row
    int lane = threadIdx.x & 63;
    if (w >= N) return;
    int b = rs[w], e = re[w];
    float acc = 0.f;
    for (int q = b; q < e; q++) acc += feat[(size_t)src[q] * 64 + lane];
    agg[(size_t)w * 64 + lane] = acc;
}

__global__ __launch_bounds__(256) void gather32_kernel(const float* __restrict__ feat,
                                                       const int* __restrict__ rs,
                                                       const int* __restrict__ re,
                                                       const int* __restrict__ src,
                                                       float* __restrict__ agg, int N) {
    int hw = (blockIdx.x * 256 + threadIdx.x) >> 5;  // half-wave id = row
    int k = threadIdx.x & 31;
    if (hw >= N) return;
    int b = rs[hw], e = re[hw];
    float acc = 0.f;
    for (int q = b; q < e; q++) acc += feat[(size_t)src[q] * 32 + k];
    agg[(size_t)hw * 32 + k] = acc;
}

// ---------------- h_out = relu(agg @ Wrel + b + hin @ Wroot) ----------------
template <int KIN>
__global__ __launch_bounds__(256) void lin_kernel(const float* __restrict__ agg,
                                                  const float* __restrict__ hin,
                                                  const float* __restrict__ Wrel,
                                                  const float* __restrict__ brel,
                                                  const float* __restrict__ Wroot,
                                                  float* __restrict__ hout, int N) {
    __shared__ float wR[KIN * 64];
    __shared__ float wO[KIN * 64];
    __shared__ float bb[64];
    int tid = threadIdx.x;
    for (int t = tid; t < KIN * 64; t += 256) { wR[t] = Wrel[t]; wO[t] = Wroot[t]; }
    if (tid < 64) bb[tid] = brel[tid];
    __syncthreads();
    int o = tid & 63, wg = tid >> 6;
    int base = blockIdx.x * 32 + wg * 8;
    for (int rr = 0; rr < 8; rr++) {
        int row = base + rr;
        if (row >= N) return;  // uniform within the wave
        float acc = bb[o];
        const float* ar = agg + (size_t)row * KIN;
        const float* hr = hin + (size_t)row * KIN;
#pragma unroll
        for (int k = 0; k < KIN; k++) acc = fmaf(ar[k], wR[k * 64 + o], acc);
#pragma unroll
        for (int k = 0; k < KIN; k++) acc = fmaf(hr[k], wO[k * 64 + o], acc);
        hout[(size_t)row * 64 + o] = fmaxf(acc, 0.f);
    }
}

// ---------------- emb = normalize(concat(x,h1,h2) @ W_e + b_e) ----------------
__global__ __launch_bounds__(256) void emb_kernel(const float* __restrict__ x,
                                                  const float* __restrict__ h1,
                                                  const float* __restrict__ h2,
                                                  const float* __restrict__ We,
                                                  const float* __restrict__ be,
                                                  float* __restrict__ emb, int N) {
    __shared__ float w[160 * 64];  // 40 KB
    __shared__ float bb[64];
    int tid = threadIdx.x;
    for (int t = tid; t < 160 * 64; t += 256) w[t] = We[t];
    if (tid < 64) bb[tid] = be[tid];
    __syncthreads();
    int o = tid & 63, wg = tid >> 6;
    int base = blockIdx.x * 32 + wg * 8;
    for (int rr = 0; rr < 8; rr++) {
        int row = base + rr;
        if (row >= N) return;  // uniform within the wave
        float acc = bb[o];
        const float* xr = x + (size_t)row * 32;
#pragma unroll
        for (int k = 0; k < 32; k++) acc = fmaf(xr[k], w[k * 64 + o], acc);
        const float* h1r = h1 + (size_t)row * 64;
#pragma unroll
        for (int k = 0; k < 64; k++) acc = fmaf(h1r[k], w[(32 + k) * 64 + o], acc);
        const float* h2r = h2 + (size_t)row * 64;
#pragma unroll
        for (int k = 0; k < 64; k++) acc = fmaf(h2r[k], w[(96 + k) * 64 + o], acc);
        float ss = acc * acc;
#pragma unroll
        for (int d = 32; d > 0; d >>= 1) ss += __shfl_xor(ss, d, 64);
        float nrm = fmaxf(sqrtf(ss), 1e-12f);
        emb[(size_t)row * 64 + o] = acc / nrm;
    }
}

// ---------------- cost: per (pair, 96-row half), cdist + masking ----------------
__global__ __launch_bounds__(256) void cost_kernel(const float* __restrict__ embS,
                                                   const float* __restrict__ embT,
                                                   const float* __restrict__ vraw,
                                                   const int* __restrict__ lenS,
                                                   const int* __restrict__ lenT,
                                                   const int* __restrict__ off,
                                                   float* __restrict__ cost, int Ns) {
    int p = blockIdx.x >> 1;
    int half = blockIdx.x & 1;
    __shared__ float sS[96 * 65];    // stride 65: bank = (row+k)%32, conflict-free
    __shared__ float sT[192 * 65];
    __shared__ float sqS[96];
    __shared__ float sqT[192];
    __shared__ __align__(16) float virt[64];
    int tid = threadIdx.x;
    int n = lenS[p], m = lenT[p];
    int offs = off[p], offt = off[PAIRS + p];

    if (tid < 64) {
        float v = vraw[tid];
        float ss = v * v;
#pragma unroll
        for (int d = 32; d > 0; d >>= 1) ss += __shfl_xor(ss, d, 64);
        virt[tid] = v / fmaxf(sqrtf(ss), 1e-12f);
    }
    __syncthreads();

    for (int t = tid; t < 96 * 16; t += 256) {
        int r = t >> 4, q = t & 15;
        int gi = offs + half * 96 + r;
        if (gi > Ns - 1) gi = Ns - 1;
        float4 vv = ((const float4*)embS)[(size_t)gi * 16 + q];
        sS[r * 65 + q * 4 + 0] = vv.x;
        sS[r * 65 + q * 4 + 1] = vv.y;
        sS[r * 65 + q * 4 + 2] = vv.z;
        sS[r * 65 + q * 4 + 3] = vv.w;
    }
    for (int t = tid; t < 192 * 16; t += 256) {
        int j = t >> 4, q = t & 15;
        float4 vv;
        if (j < m) vv = ((const float4*)embT)[(size_t)(offt + j) * 16 + q];
        else       vv = ((const float4*)virt)[q];
        sT[j * 65 + q * 4 + 0] = vv.x;
        sT[j * 65 + q * 4 + 1] = vv.y;
        sT[j * 65 + q * 4 + 2] = vv.z;
        sT[j * 65 + q * 4 + 3] = vv.w;
    }
    __syncthreads();

    for (int r = tid; r < 96; r += 256) {
        float s = 0.f;
#pragma unroll
        for (int k = 0; k < 64; k++) { float a = sS[r * 65 + k]; s = fmaf(a, a, s); }
        sqS[r] = s;
    }
    for (int j = tid; j < 192; j += 256) {
        float s = 0.f;
#pragma unroll
        for (int k = 0; k < 64; k++) { float a = sT[j * 65 + k]; s = fmaf(a, a, s); }
        sqT[j] = s;
    }
    __syncthreads();

    int ti = tid & 15, tj = tid >> 4;
    int ibase = ti * 6, jbase = tj * 12;
    float acc[6][12];
#pragma unroll
    for (int r = 0; r < 6; r++)
#pragma unroll
        for (int c = 0; c < 12; c++) acc[r][c] = 0.f;

    for (int k = 0; k < 64; k++) {
        float sv[6], tv[12];
#pragma unroll
        for (int r = 0; r < 6; r++) sv[r] = sS[(ibase + r) * 65 + k];
#pragma unroll
        for (int c = 0; c < 12; c++) tv[c] = sT[(jbase + c) * 65 + k];
#pragma unroll
        for (int r = 0; r < 6; r++)
#pragma unroll
            for (int c = 0; c < 12; c++) acc[r][c] = fmaf(sv[r], tv[c], acc[r][c]);
    }

    int i0 = half * 96;
#pragma unroll
    for (int r = 0; r < 6; r++) {
        int i = i0 + ibase + r;
        bool rv = i < n;
        float sqi = sqS[ibase + r];
        float* orow = cost + ((size_t)p * MAXN + i) * MAXN + jbase;
        float tmp[12];
#pragma unroll
        for (int c = 0; c < 12; c++) {
            int j = jbase + c;
            float cd = sqrtf(fmaxf(sqi + sqT[j] - 2.f * acc[r][c], 1e-12f));
            bool cv = j < n;
            tmp[c] = (rv && cv) ? cd : ((!rv && !cv) ? 0.f : 1000.f);
        }
#pragma unroll
        for (int q = 0; q < 3; q++)
            ((float4*)orow)[q] = make_float4(tmp[4 * q], tmp[4 * q + 1], tmp[4 * q + 2], tmp[4 * q + 3]);
    }
}

// ---------------- Sinkhorn (K resident in LDS) + gamma + geds2 ----------------
__global__ __launch_bounds__(256) void sinkhorn_kernel(const float* __restrict__ cost,
                                                       float* __restrict__ gamma,
                                                       float* __restrict__ geds2,
                                                       const int* __restrict__ lenS,
                                                       const int* __restrict__ lenT) {
    int p = blockIdx.x;
    __shared__ float K[MAXN * 193];  // stride 193: bank=(i+j)%32, both matvecs conflict-free
    __shared__ float u[MAXN];
    __shared__ float v[MAXN];
    __shared__ float red[4];
    int tid = threadIdx.x;
    const float* cp = cost + (size_t)p * MAXN * MAXN;

    for (int t = tid; t < MAXN * MAXN; t += 256) {
        int i = t / MAXN, j = t - i * MAXN;
        K[i * 193 + j] = expf(-10.f * cp[t]);
    }
    for (int t = tid; t < MAXN; t += 256) u[t] = 1.f / 192.f;

    for (int it = 0; it < 8; it++) {
        __syncthreads();
        if (tid < MAXN) {
            float s = 0.f;
            for (int i = 0; i < MAXN; i++) s = fmaf(K[i * 193 + tid], u[i], s);
            v[tid] = 1.f / s;
        }
        __syncthreads();
        if (tid < MAXN) {
            float s = 0.f;
            for (int j = 0; j < MAXN; j++) s = fmaf(K[tid * 193 + j], v[j], s);
            u[tid] = 1.f / s;
        }
    }
    __syncthreads();

    float acc = 0.f;
    float* gp = gamma + (size_t)p * MAXN * MAXN;
    for (int t = tid; t < MAXN * MAXN; t += 256) {
        int i = t / MAXN, j = t - i * MAXN;
        float Kij = K[i * 193 + j];
        float g = u[i] * Kij * v[j];
        gp[t] = g;
        if (Kij > 0.f) acc = fmaf(g, -0.1f * logf(Kij), acc);
    }
#pragma unroll
    for (int d = 32; d > 0; d >>= 1) acc += __shfl_xor(acc, d, 64);
    int lane = tid & 63, wv = tid >> 6;
    if (lane == 0) red[wv] = acc;
    __syncthreads();
    if (tid == 0) {
        float g = red[0] + red[1] + red[2] + red[3];
        geds2[p] = g / (float)(lenS[p] + lenT[p]);
    }
}

extern "C" void kernel_launch(void* const* d_in, const int* in_sizes, int n_in,
                              void* d_out, int out_size, void* d_ws, size_t ws_size,
                              hipStream_t stream) {
    const float* x_s     = (const float*)d_in[0];
    const float* x_t     = (const float*)d_in[1];
    const float* W_rel0  = (const float*)d_in[2];
    const float* b_rel0  = (const float*)d_in[3];
    const float* W_root0 = (const float*)d_in[4];
    const float* W_rel1  = (const float*)d_in[5];
    const float* b_rel1  = (const float*)d_in[6];
    const float* W_root1 = (const float*)d_in[7];
    const float* W_e     = (const float*)d_in[8];
    const float* b_e     = (const float*)d_in[9];
    const float* virt    = (const float*)d_in[10];
    const int*   ei_s    = (const int*)d_in[11];
    const int*   ei_t    = (const int*)d_in[12];
    const int*   len_s   = (const int*)d_in[13];
    const int*   len_t   = (const int*)d_in[14];

    int Ns = in_sizes[0] / 32;
    int Nt = in_sizes[1] / 32;
    int Es = in_sizes[11] / 2;
    int Et = in_sizes[12] / 2;

    // ---- workspace layout ----
    char* w = (char*)d_ws;
    int* off = (int*)w;               w += 1024 * 4;
    int* bsumS = (int*)w;             w += 256 * 4;
    int* bsumT = (int*)w;             w += 256 * 4;
    int* rsS = (int*)w;               w += (size_t)Ns * 4;   // rowstart (begin)
    int* curS = (int*)w;              w += (size_t)Ns * 4;   // cursor -> row end after fill
    int* srcS = (int*)w;              w += (size_t)Es * 4;
    int* rsT = (int*)w;               w += (size_t)Nt * 4;
    int* curT = (int*)w;              w += (size_t)Nt * 4;
    int* srcT = (int*)w;              w += (size_t)Et * 4;
    w = (char*)(((size_t)w + 255) & ~(size_t)255);
    float* aggS = (float*)w;          w += (size_t)Ns * 64 * 4;   // also final emb_s
    float* h1S  = (float*)w;          w += (size_t)Ns * 64 * 4;
    float* h2S  = (float*)w;          w += (size_t)Ns * 64 * 4;
    float* aggT = (float*)w;          w += (size_t)Nt * 64 * 4;   // also final emb_t
    float* h1T  = (float*)w;          w += (size_t)Nt * 64 * 4;
    float* h2T  = (float*)w;          w += (size_t)Nt * 64 * 4;

    float* out_gamma = (float*)d_out;
    float* out_cost  = out_gamma + (size_t)PAIRS * MAXN * MAXN;
    float* out_geds  = out_cost + (size_t)PAIRS * MAXN * MAXN;

    offsets_kernel<<<1, PAIRS, 0, stream>>>(len_s, len_t, off);

    // ---- CSR build: source graph ----
    hipMemsetAsync(rsS, 0, (size_t)Ns * 4, stream);
    count_kernel<<<(Es + 255) / 256, 256, 0, stream>>>(ei_s, rsS, Es);
    int nb_s = (Ns + 1023) / 1024;
    scan1_kernel<<<nb_s, 256, 0, stream>>>(rsS, bsumS, Ns);
    scan2_kernel<<<1, 64, 0, stream>>>(bsumS, nb_s);
    scan3_kernel<<<(Ns + 255) / 256, 256, 0, stream>>>(rsS, bsumS, curS, Ns);
    fill_kernel<<<(Es + 255) / 256, 256, 0, stream>>>(ei_s, curS, srcS, Es);

    // ---- CSR build: target graph ----
    hipMemsetAsync(rsT, 0, (size_t)Nt * 4, stream);
    count_kernel<<<(Et + 255) / 256, 256, 0, stream>>>(ei_t, rsT, Et);
    int nb_t = (Nt + 1023) / 1024;
    scan1_kernel<<<nb_t, 256, 0, stream>>>(rsT, bsumT, Nt);
    scan2_kernel<<<1, 64, 0, stream>>>(bsumT, nb_t);
    scan3_kernel<<<(Nt + 255) / 256, 256, 0, stream>>>(rsT, bsumT, curT, Nt);
    fill_kernel<<<(Et + 255) / 256, 256, 0, stream>>>(ei_t, curT, srcT, Et);

    // ---- source graph GNN ----
    gather32_kernel<<<(int)(((long long)Ns * 32 + 255) / 256), 256, 0, stream>>>(x_s, rsS, curS, srcS, aggS, Ns);
    lin_kernel<32><<<(Ns + 31) / 32, 256, 0, stream>>>(aggS, x_s, W_rel0, b_rel0, W_root0, h1S, Ns);
    gather64_kernel<<<(int)(((long long)Ns * 64 + 255) / 256), 256, 0, stream>>>(h1S, rsS, curS, srcS, aggS, Ns);
    lin_kernel<64><<<(Ns + 31) / 32, 256, 0, stream>>>(aggS, h1S, W_rel1, b_rel1, W_root1, h2S, Ns);
    emb_kernel<<<(Ns + 31) / 32, 256, 0, stream>>>(x_s, h1S, h2S, W_e, b_e, aggS, Ns);  // emb_s -> aggS

    // ---- target graph GNN ----
    gather32_kernel<<<(int)(((long long)Nt * 32 + 255) / 256), 256, 0, stream>>>(x_t, rsT, curT, srcT, aggT, Nt);
    lin_kernel<32><<<(Nt + 31) / 32, 256, 0, stream>>>(aggT, x_t, W_rel0, b_rel0, W_root0, h1T, Nt);
    gather64_kernel<<<(int)(((long long)Nt * 64 + 255) / 256), 256, 0, stream>>>(h1T, rsT, curT, srcT, aggT, Nt);
    lin_kernel<64><<<(Nt + 31) / 32, 256, 0, stream>>>(aggT, h1T, W_rel1, b_rel1, W_root1, h2T, Nt);
    emb_kernel<<<(Nt + 31) / 32, 256, 0, stream>>>(x_t, h1T, h2T, W_e, b_e, aggT, Nt);  // emb_t -> aggT

    // ---- cost + sinkhorn ----
    cost_kernel<<<PAIRS * 2, 256, 0, stream>>>(aggS, aggT, virt, len_s, len_t, off, out_cost, Ns);
    sinkhorn_kernel<<<PAIRS, 256, 0, stream>>>(out_cost, out_gamma, out_geds, len_s, len_t);
}

// Round 3
// 777.906 us; speedup vs baseline: 1.1934x; 1.1632x over previous
//
#include <hip/hip_runtime.h>
#include <math.h>

#define PAIRS 512
#define MAXN 192

// ---------------- offsets: exclusive prefix sums of len_s / len_t (shfl scan) ----------------
__global__ void offsets_kernel(const int* __restrict__ ls, const int* __restrict__ lt,
                               int* __restrict__ off) {
    __shared__ int wa[8], wb[8];
    int t = threadIdx.x;  // 512
    int a = ls[t], b = lt[t];
    int ia = a, ib = b;
#pragma unroll
    for (int d = 1; d < 64; d <<= 1) {
        int xa = __shfl_up(ia, d, 64);
        int xb = __shfl_up(ib, d, 64);
        if ((t & 63) >= d) { ia += xa; ib += xb; }
    }
    if ((t & 63) == 63) { wa[t >> 6] = ia; wb[t >> 6] = ib; }
    __syncthreads();
    int pa = 0, pb = 0;
    for (int w = 0; w < (t >> 6); w++) { pa += wa[w]; pb += wb[w]; }
    off[t] = pa + ia - a;          // exclusive
    off[PAIRS + t] = pb + ib - b;
}

// ================= CSR build over combined row space [0,Ns) ∪ [Ns,Ns+Nt) =================
__global__ __launch_bounds__(256) void count2_kernel(const int* __restrict__ eiS,
                                                     const int* __restrict__ eiT,
                                                     int* __restrict__ cnt,
                                                     int Es, int Et, int split) {
    int e = blockIdx.x * 256 + threadIdx.x;
    if (e < Es) atomicAdd(&cnt[eiS[Es + e]], 1);
    else if (e < Es + Et) atomicAdd(&cnt[split + eiT[Et + (e - Es)]], 1);
}

// in-place exclusive scan, 1024 ints per block; blockSums[b] = block total
__global__ __launch_bounds__(256) void scan1_kernel(int* __restrict__ data,
                                                    int* __restrict__ blockSums, int N) {
    __shared__ int sc[256];
    int t = threadIdx.x;
    int base = blockIdx.x * 1024;
    int v[4];
    int s = 0;
#pragma unroll
    for (int q = 0; q < 4; q++) {
        int i = base + t * 4 + q;
        v[q] = (i < N) ? data[i] : 0;
        s += v[q];
    }
    sc[t] = s;
    __syncthreads();
    for (int d = 1; d < 256; d <<= 1) {
        int x = (t >= d) ? sc[t - d] : 0;
        __syncthreads();
        sc[t] += x;
        __syncthreads();
    }
    int excl = sc[t] - s;
#pragma unroll
    for (int q = 0; q < 4; q++) {
        int i = base + t * 4 + q;
        if (i < N) { data[i] = excl; excl += v[q]; }
    }
    if (t == 255) blockSums[blockIdx.x] = sc[255];
}

// parallel exclusive scan of up to 256 block sums (replaces 1-thread serial scan)
__global__ void scan2_kernel(int* __restrict__ blockSums, int B) {
    __shared__ int sh[256];
    int t = threadIdx.x;  // 256
    int v = (t < B) ? blockSums[t] : 0;
    sh[t] = v;
    __syncthreads();
    for (int d = 1; d < 256; d <<= 1) {
        int x = (t >= d) ? sh[t - d] : 0;
        __syncthreads();
        sh[t] += x;
        __syncthreads();
    }
    if (t < B) blockSums[t] = sh[t] - v;
}

__global__ __launch_bounds__(256) void scan3_kernel(int* __restrict__ data,
                                                    const int* __restrict__ blockSums,
                                                    int* __restrict__ cursor, int N) {
    int i = blockIdx.x * 256 + threadIdx.x;
    if (i < N) {
        int v = data[i] + blockSums[i >> 10];
        data[i] = v;
        cursor[i] = v;
    }
}

__global__ __launch_bounds__(256) void fill2_kernel(const int* __restrict__ eiS,
                                                    const int* __restrict__ eiT,
                                                    int* __restrict__ cursor,
                                                    int* __restrict__ src,
                                                    int Es, int Et, int split) {
    int e = blockIdx.x * 256 + threadIdx.x;
    if (e < Es) {
        int p = atomicAdd(&cursor[eiS[Es + e]], 1);
        src[p] = eiS[e];                       // S-local source index
    } else if (e < Es + Et) {
        int ee = e - Es;
        int p = atomicAdd(&cursor[split + eiT[Et + ee]], 1);
        src[p] = eiT[ee];                      // T-local source index
    }
}
// after fill: cursor[r] == row-end, data/rowstart[r] == row-begin

// ================= gather aggregation (combined rows, shfl-prefetched indices) =================
template <int F>
__global__ __launch_bounds__(256) void gather_kernel(const float* __restrict__ featA,
                                                     const float* __restrict__ featB,
                                                     int split,
                                                     const int* __restrict__ rs,
                                                     const int* __restrict__ re,
                                                     const int* __restrict__ src,
                                                     float* __restrict__ agg, int N) {
    int gid = blockIdx.x * 256 + threadIdx.x;
    int row = gid / F;
    int lane = threadIdx.x & (F - 1);
    if (row >= N) return;
    int b = rs[row], e = re[row];
    int cnt = e - b;
    const float* feat = (row < split) ? featA : featB;
    int pre = cnt < F ? cnt : F;
    int sidx = (lane < cnt) ? src[b + lane] : 0;   // batch the index loads
    float acc = 0.f;
    for (int q = 0; q < pre; q++) {
        int s = __shfl(sidx, q, F);
        acc += feat[(size_t)s * F + lane];
    }
    for (int q = b + F; q < e; q++) acc += feat[(size_t)src[q] * F + lane];  // rare tail
    agg[(size_t)row * F + lane] = acc;
}

// ---------------- h_out = relu(agg @ Wrel + b + hin @ Wroot), combined rows ----------------
template <int KIN>
__global__ __launch_bounds__(256) void lin_kernel(const float* __restrict__ agg,
                                                  const float* __restrict__ hinA,
                                                  const float* __restrict__ hinB,
                                                  int split,
                                                  const float* __restrict__ Wrel,
                                                  const float* __restrict__ brel,
                                                  const float* __restrict__ Wroot,
                                                  float* __restrict__ hout, int N) {
    __shared__ float wR[KIN * 64];
    __shared__ float wO[KIN * 64];
    __shared__ float bb[64];
    int tid = threadIdx.x;
    for (int t = tid; t < KIN * 64; t += 256) { wR[t] = Wrel[t]; wO[t] = Wroot[t]; }
    if (tid < 64) bb[tid] = brel[tid];
    __syncthreads();
    int o = tid & 63, wg = tid >> 6;
    int base = blockIdx.x * 32 + wg * 8;
    for (int rr = 0; rr < 8; rr++) {
        int row = base + rr;
        if (row >= N) return;  // uniform within the wave
        float acc = bb[o];
        const float* ar = agg + (size_t)row * KIN;
        const float* hr = (row < split) ? hinA + (size_t)row * KIN
                                        : hinB + (size_t)(row - split) * KIN;
#pragma unroll
        for (int k = 0; k < KIN; k++) acc = fmaf(ar[k], wR[k * 64 + o], acc);
#pragma unroll
        for (int k = 0; k < KIN; k++) acc = fmaf(hr[k], wO[k * 64 + o], acc);
        hout[(size_t)row * 64 + o] = fmaxf(acc, 0.f);
    }
}

// ---------------- emb = normalize(concat(x,h1,h2) @ W_e + b_e), combined rows ----------------
__global__ __launch_bounds__(256) void emb_kernel(const float* __restrict__ xA,
                                                  const float* __restrict__ xB,
                                                  int split,
                                                  const float* __restrict__ h1,
                                                  const float* __restrict__ h2,
                                                  const float* __restrict__ We,
                                                  const float* __restrict__ be,
                                                  float* __restrict__ emb, int N) {
    __shared__ float w[160 * 64];  // 40 KB
    __shared__ float bb[64];
    int tid = threadIdx.x;
    for (int t = tid; t < 160 * 64; t += 256) w[t] = We[t];
    if (tid < 64) bb[tid] = be[tid];
    __syncthreads();
    int o = tid & 63, wg = tid >> 6;
    int base = blockIdx.x * 32 + wg * 8;
    for (int rr = 0; rr < 8; rr++) {
        int row = base + rr;
        if (row >= N) return;  // uniform within the wave
        float acc = bb[o];
        const float* xr = (row < split) ? xA + (size_t)row * 32
                                        : xB + (size_t)(row - split) * 32;
#pragma unroll
        for (int k = 0; k < 32; k++) acc = fmaf(xr[k], w[k * 64 + o], acc);
        const float* h1r = h1 + (size_t)row * 64;
#pragma unroll
        for (int k = 0; k < 64; k++) acc = fmaf(h1r[k], w[(32 + k) * 64 + o], acc);
        const float* h2r = h2 + (size_t)row * 64;
#pragma unroll
        for (int k = 0; k < 64; k++) acc = fmaf(h2r[k], w[(96 + k) * 64 + o], acc);
        float ss = acc * acc;
#pragma unroll
        for (int d = 32; d > 0; d >>= 1) ss += __shfl_xor(ss, d, 64);
        float nrm = fmaxf(sqrtf(ss), 1e-12f);
        emb[(size_t)row * 64 + o] = acc / nrm;
    }
}

// ---------------- cost: per (pair, 96-row half), cdist + masking ----------------
__global__ __launch_bounds__(256) void cost_kernel(const float* __restrict__ embS,
                                                   const float* __restrict__ embT,
                                                   const float* __restrict__ vraw,
                                                   const int* __restrict__ lenS,
                                                   const int* __restrict__ lenT,
                                                   const int* __restrict__ off,
                                                   float* __restrict__ cost, int Ns) {
    int p = blockIdx.x >> 1;
    int half = blockIdx.x & 1;
    __shared__ float sS[96 * 65];    // stride 65: bank = (row+k)%32, conflict-free
    __shared__ float sT[192 * 65];
    __shared__ float sqS[96];
    __shared__ float sqT[192];
    __shared__ __align__(16) float virt[64];
    int tid = threadIdx.x;
    int n = lenS[p], m = lenT[p];
    int offs = off[p], offt = off[PAIRS + p];

    if (tid < 64) {
        float v = vraw[tid];
        float ss = v * v;
#pragma unroll
        for (int d = 32; d > 0; d >>= 1) ss += __shfl_xor(ss, d, 64);
        virt[tid] = v / fmaxf(sqrtf(ss), 1e-12f);
    }
    __syncthreads();

    for (int t = tid; t < 96 * 16; t += 256) {
        int r = t >> 4, q = t & 15;
        int gi = offs + half * 96 + r;
        if (gi > Ns - 1) gi = Ns - 1;
        float4 vv = ((const float4*)embS)[(size_t)gi * 16 + q];
        sS[r * 65 + q * 4 + 0] = vv.x;
        sS[r * 65 + q * 4 + 1] = vv.y;
        sS[r * 65 + q * 4 + 2] = vv.z;
        sS[r * 65 + q * 4 + 3] = vv.w;
    }
    for (int t = tid; t < 192 * 16; t += 256) {
        int j = t >> 4, q = t & 15;
        float4 vv;
        if (j < m) vv = ((const float4*)embT)[(size_t)(offt + j) * 16 + q];
        else       vv = ((const float4*)virt)[q];
        sT[j * 65 + q * 4 + 0] = vv.x;
        sT[j * 65 + q * 4 + 1] = vv.y;
        sT[j * 65 + q * 4 + 2] = vv.z;
        sT[j * 65 + q * 4 + 3] = vv.w;
    }
    __syncthreads();

    for (int r = tid; r < 96; r += 256) {
        float s = 0.f;
#pragma unroll
        for (int k = 0; k < 64; k++) { float a = sS[r * 65 + k]; s = fmaf(a, a, s); }
        sqS[r] = s;
    }
    for (int j = tid; j < 192; j += 256) {
        float s = 0.f;
#pragma unroll
        for (int k = 0; k < 64; k++) { float a = sT[j * 65 + k]; s = fmaf(a, a, s); }
        sqT[j] = s;
    }
    __syncthreads();

    int ti = tid & 15, tj = tid >> 4;
    int ibase = ti * 6, jbase = tj * 12;
    float acc[6][12];
#pragma unroll
    for (int r = 0; r < 6; r++)
#pragma unroll
        for (int c = 0; c < 12; c++) acc[r][c] = 0.f;

    for (int k = 0; k < 64; k++) {
        float sv[6], tv[12];
#pragma unroll
        for (int r = 0; r < 6; r++) sv[r] = sS[(ibase + r) * 65 + k];
#pragma unroll
        for (int c = 0; c < 12; c++) tv[c] = sT[(jbase + c) * 65 + k];
#pragma unroll
        for (int r = 0; r < 6; r++)
#pragma unroll
            for (int c = 0; c < 12; c++) acc[r][c] = fmaf(sv[r], tv[c], acc[r][c]);
    }

    int i0 = half * 96;
#pragma unroll
    for (int r = 0; r < 6; r++) {
        int i = i0 + ibase + r;
        bool rv = i < n;
        float sqi = sqS[ibase + r];
        float* orow = cost + ((size_t)p * MAXN + i) * MAXN + jbase;
        float tmp[12];
#pragma unroll
        for (int c = 0; c < 12; c++) {
            int j = jbase + c;
            float cd = sqrtf(fmaxf(sqi + sqT[j] - 2.f * acc[r][c], 1e-12f));
            bool cv = j < n;
            tmp[c] = (rv && cv) ? cd : ((!rv && !cv) ? 0.f : 1000.f);
        }
#pragma unroll
        for (int q = 0; q < 3; q++)
            ((float4*)orow)[q] = make_float4(tmp[4 * q], tmp[4 * q + 1], tmp[4 * q + 2], tmp[4 * q + 3]);
    }
}

// ---------------- Sinkhorn: 1024 threads, 4-way striped matvec, K in LDS ----------------
__global__ __launch_bounds__(1024) void sinkhorn_kernel(const float* __restrict__ cost,
                                                        float* __restrict__ gamma,
                                                        float* __restrict__ geds2,
                                                        const int* __restrict__ lenS,
                                                        const int* __restrict__ lenT) {
    int p = blockIdx.x;
    __shared__ float K[MAXN * 193];   // 148224 B; stride 193: both access dirs conflict-free
    __shared__ float part[4 * MAXN];  // striped partial sums
    __shared__ float u[MAXN];
    __shared__ float v[MAXN];
    __shared__ float wsum[16];
    int tid = threadIdx.x;
    const float* cp = cost + (size_t)p * MAXN * MAXN;

    for (int t = tid; t < MAXN * MAXN; t += 1024) {
        int i = t / MAXN, j = t - i * MAXN;
        K[i * 193 + j] = expf(-10.f * cp[t]);
    }
    if (tid < MAXN) u[tid] = 1.f / 192.f;

    int g = tid >> 8;       // stripe 0..3
    int r = tid & 255;      // 0..255 (active if < 192)
    int base = g * 48;

    for (int it = 0; it < 8; it++) {
        __syncthreads();
        if (r < MAXN) {  // v_j partials: sum over i-stripe of K[i][j] u_i
            float s = 0.f;
#pragma unroll
            for (int q = 0; q < 48; q++) { int i = base + q; s = fmaf(K[i * 193 + r], u[i], s); }
            part[g * MAXN + r] = s;
        }
        __syncthreads();
        if (tid < MAXN)
            v[tid] = 1.f / (part[tid] + part[MAXN + tid] + part[2 * MAXN + tid] + part[3 * MAXN + tid]);
        __syncthreads();
        if (r < MAXN) {  // u_i partials: sum over j-stripe of K[i][j] v_j
            float s = 0.f;
#pragma unroll
            for (int q = 0; q < 48; q++) { int j = base + q; s = fmaf(K[r * 193 + j], v[j], s); }
            part[g * MAXN + r] = s;
        }
        __syncthreads();
        if (tid < MAXN)
            u[tid] = 1.f / (part[tid] + part[MAXN + tid] + part[2 * MAXN + tid] + part[3 * MAXN + tid]);
    }
    __syncthreads();

    float acc = 0.f;
    float* gp = gamma + (size_t)p * MAXN * MAXN;
    for (int t = tid; t < MAXN * MAXN; t += 1024) {
        int i = t / MAXN, j = t - i * MAXN;
        float Kij = K[i * 193 + j];
        float gg = u[i] * Kij * v[j];
        gp[t] = gg;
        if (Kij > 0.f) acc = fmaf(gg, -0.1f * logf(Kij), acc);  // cost = -0.1*log(K)
    }
#pragma unroll
    for (int d = 32; d > 0; d >>= 1) acc += __shfl_xor(acc, d, 64);
    if ((tid & 63) == 0) wsum[tid >> 6] = acc;
    __syncthreads();
    if (tid == 0) {
        float s = 0.f;
        for (int q = 0; q < 16; q++) s += wsum[q];
        geds2[p] = s / (float)(lenS[p] + lenT[p]);
    }
}

extern "C" void kernel_launch(void* const* d_in, const int* in_sizes, int n_in,
                              void* d_out, int out_size, void* d_ws, size_t ws_size,
                              hipStream_t stream) {
    const float* x_s     = (const float*)d_in[0];
    const float* x_t     = (const float*)d_in[1];
    const float* W_rel0  = (const float*)d_in[2];
    const float* b_rel0  = (const float*)d_in[3];
    const float* W_root0 = (const float*)d_in[4];
    const float* W_rel1  = (const float*)d_in[5];
    const float* b_rel1  = (const float*)d_in[6];
    const float* W_root1 = (const float*)d_in[7];
    const float* W_e     = (const float*)d_in[8];
    const float* b_e     = (const float*)d_in[9];
    const float* virt    = (const float*)d_in[10];
    const int*   ei_s    = (const int*)d_in[11];
    const int*   ei_t    = (const int*)d_in[12];
    const int*   len_s   = (const int*)d_in[13];
    const int*   len_t   = (const int*)d_in[14];

    int Ns = in_sizes[0] / 32;
    int Nt = in_sizes[1] / 32;
    int Es = in_sizes[11] / 2;
    int Et = in_sizes[12] / 2;
    int Ntot = Ns + Nt;
    int Etot = Es + Et;

    // ---- workspace layout ----
    char* w = (char*)d_ws;
    int* off  = (int*)w;              w += 1024 * 4;
    int* bsum = (int*)w;              w += 256 * 4;
    int* rs   = (int*)w;              w += (size_t)Ntot * 4;  // row begin
    int* cur  = (int*)w;              w += (size_t)Ntot * 4;  // cursor -> row end after fill
    int* src  = (int*)w;              w += (size_t)Etot * 4;
    w = (char*)(((size_t)w + 255) & ~(size_t)255);
    float* agg = (float*)w;           w += (size_t)Ntot * 64 * 4;  // also final emb
    float* h1  = (float*)w;           w += (size_t)Ntot * 64 * 4;
    float* h2  = (float*)w;           w += (size_t)Ntot * 64 * 4;

    float* out_gamma = (float*)d_out;
    float* out_cost  = out_gamma + (size_t)PAIRS * MAXN * MAXN;
    float* out_geds  = out_cost + (size_t)PAIRS * MAXN * MAXN;

    offsets_kernel<<<1, PAIRS, 0, stream>>>(len_s, len_t, off);

    // ---- combined CSR build ----
    hipMemsetAsync(rs, 0, (size_t)Ntot * 4, stream);
    count2_kernel<<<(Etot + 255) / 256, 256, 0, stream>>>(ei_s, ei_t, rs, Es, Et, Ns);
    int nb = (Ntot + 1023) / 1024;
    scan1_kernel<<<nb, 256, 0, stream>>>(rs, bsum, Ntot);
    scan2_kernel<<<1, 256, 0, stream>>>(bsum, nb);
    scan3_kernel<<<(Ntot + 255) / 256, 256, 0, stream>>>(rs, bsum, cur, Ntot);
    fill2_kernel<<<(Etot + 255) / 256, 256, 0, stream>>>(ei_s, ei_t, cur, src, Es, Et, Ns);

    // ---- combined GNN ----
    gather_kernel<32><<<(int)(((long long)Ntot * 32 + 255) / 256), 256, 0, stream>>>(
        x_s, x_t, Ns, rs, cur, src, agg, Ntot);
    lin_kernel<32><<<(Ntot + 31) / 32, 256, 0, stream>>>(
        agg, x_s, x_t, Ns, W_rel0, b_rel0, W_root0, h1, Ntot);
    gather_kernel<64><<<(int)(((long long)Ntot * 64 + 255) / 256), 256, 0, stream>>>(
        h1, h1 + (size_t)Ns * 64, Ns, rs, cur, src, agg, Ntot);
    lin_kernel<64><<<(Ntot + 31) / 32, 256, 0, stream>>>(
        agg, h1, h1 + (size_t)Ns * 64, Ns, W_rel1, b_rel1, W_root1, h2, Ntot);
    emb_kernel<<<(Ntot + 31) / 32, 256, 0, stream>>>(
        x_s, x_t, Ns, h1, h2, W_e, b_e, agg, Ntot);  // emb -> agg (S rows then T rows)

    // ---- cost + sinkhorn ----
    cost_kernel<<<PAIRS * 2, 256, 0, stream>>>(
        agg, agg + (size_t)Ns * 64, virt, len_s, len_t, off, out_cost, Ns);
    sinkhorn_kernel<<<PAIRS, 1024, 0, stream>>>(out_cost, out_gamma, out_geds, len_s, len_t);
}

// Round 4
// 612.206 us; speedup vs baseline: 1.5164x; 1.2707x over previous
//
#include <hip/hip_runtime.h>
#include <math.h>

#define PAIRS 512
#define MAXN 192

// ---------------- offsets: exclusive prefix sums of len_s / len_t (shfl scan) ----------------
__global__ void offsets_kernel(const int* __restrict__ ls, const int* __restrict__ lt,
                               int* __restrict__ off) {
    __shared__ int wa[8], wb[8];
    int t = threadIdx.x;  // 512
    int a = ls[t], b = lt[t];
    int ia = a, ib = b;
#pragma unroll
    for (int d = 1; d < 64; d <<= 1) {
        int xa = __shfl_up(ia, d, 64);
        int xb = __shfl_up(ib, d, 64);
        if ((t & 63) >= d) { ia += xa; ib += xb; }
    }
    if ((t & 63) == 63) { wa[t >> 6] = ia; wb[t >> 6] = ib; }
    __syncthreads();
    int pa = 0, pb = 0;
    for (int w = 0; w < (t >> 6); w++) { pa += wa[w]; pb += wb[w]; }
    off[t] = pa + ia - a;          // exclusive
    off[PAIRS + t] = pb + ib - b;
}

// ================= CSR build over combined row space [0,Ns) ∪ [Ns,Ns+Nt) =================
__global__ __launch_bounds__(256) void count2_kernel(const int* __restrict__ eiS,
                                                     const int* __restrict__ eiT,
                                                     int* __restrict__ cnt,
                                                     int Es, int Et, int split) {
    int e = blockIdx.x * 256 + threadIdx.x;
    if (e < Es) atomicAdd(&cnt[eiS[Es + e]], 1);
    else if (e < Es + Et) atomicAdd(&cnt[split + eiT[Et + (e - Es)]], 1);
}

__global__ __launch_bounds__(256) void scan1_kernel(int* __restrict__ data,
                                                    int* __restrict__ blockSums, int N) {
    __shared__ int sc[256];
    int t = threadIdx.x;
    int base = blockIdx.x * 1024;
    int v[4];
    int s = 0;
#pragma unroll
    for (int q = 0; q < 4; q++) {
        int i = base + t * 4 + q;
        v[q] = (i < N) ? data[i] : 0;
        s += v[q];
    }
    sc[t] = s;
    __syncthreads();
    for (int d = 1; d < 256; d <<= 1) {
        int x = (t >= d) ? sc[t - d] : 0;
        __syncthreads();
        sc[t] += x;
        __syncthreads();
    }
    int excl = sc[t] - s;
#pragma unroll
    for (int q = 0; q < 4; q++) {
        int i = base + t * 4 + q;
        if (i < N) { data[i] = excl; excl += v[q]; }
    }
    if (t == 255) blockSums[blockIdx.x] = sc[255];
}

__global__ void scan2_kernel(int* __restrict__ blockSums, int B) {
    __shared__ int sh[256];
    int t = threadIdx.x;  // 256
    int v = (t < B) ? blockSums[t] : 0;
    sh[t] = v;
    __syncthreads();
    for (int d = 1; d < 256; d <<= 1) {
        int x = (t >= d) ? sh[t - d] : 0;
        __syncthreads();
        sh[t] += x;
        __syncthreads();
    }
    if (t < B) blockSums[t] = sh[t] - v;
}

__global__ __launch_bounds__(256) void scan3_kernel(int* __restrict__ data,
                                                    const int* __restrict__ blockSums,
                                                    int* __restrict__ cursor, int N) {
    int i = blockIdx.x * 256 + threadIdx.x;
    if (i < N) {
        int v = data[i] + blockSums[i >> 10];
        data[i] = v;
        cursor[i] = v;
    }
}

__global__ __launch_bounds__(256) void fill2_kernel(const int* __restrict__ eiS,
                                                    const int* __restrict__ eiT,
                                                    int* __restrict__ cursor,
                                                    int* __restrict__ src,
                                                    int Es, int Et, int split) {
    int e = blockIdx.x * 256 + threadIdx.x;
    if (e < Es) {
        int p = atomicAdd(&cursor[eiS[Es + e]], 1);
        src[p] = eiS[e];
    } else if (e < Es + Et) {
        int ee = e - Es;
        int p = atomicAdd(&cursor[split + eiT[Et + ee]], 1);
        src[p] = eiT[ee];
    }
}

// ================= gather aggregation (combined rows) =================
template <int F>
__global__ __launch_bounds__(256) void gather_kernel(const float* __restrict__ featA,
                                                     const float* __restrict__ featB,
                                                     int split,
                                                     const int* __restrict__ rs,
                                                     const int* __restrict__ re,
                                                     const int* __restrict__ src,
                                                     float* __restrict__ agg, int N) {
    int gid = blockIdx.x * 256 + threadIdx.x;
    int row = gid / F;
    int lane = threadIdx.x & (F - 1);
    if (row >= N) return;
    int b = rs[row], e = re[row];
    int cnt = e - b;
    const float* feat = (row < split) ? featA : featB;
    int pre = cnt < F ? cnt : F;
    int sidx = (lane < cnt) ? src[b + lane] : 0;
    float acc = 0.f;
    for (int q = 0; q < pre; q++) {
        int s = __shfl(sidx, q, F);
        acc += feat[(size_t)s * F + lane];
    }
    for (int q = b + F; q < e; q++) acc += feat[(size_t)src[q] * F + lane];
    agg[(size_t)row * F + lane] = acc;
}

// ================= tiled dense GEMMs: 64 rows × 64 outs / block, K-chunk ≤ 64 =================
// thread map: i = tid&15 -> rows 4i..4i+3 ; j = tid>>4 -> outs 4j..4j+3
// LDS: A[64][65] (pad: bank=(r+k)%32, conflict-free) + W chunk as float4 k-major [64][16]

// h_out = relu([agg | hin] @ [Wrel ; Wroot] + b)   (K' = 2*KIN, chunks of 64)
template <int KIN>
__global__ __launch_bounds__(256) void lin_gemm_kernel(const float* __restrict__ agg,
    const float* __restrict__ hinA, const float* __restrict__ hinB, int split,
    const float* __restrict__ Wrel, const float* __restrict__ brel,
    const float* __restrict__ Wroot, float* __restrict__ hout, int N) {
    __shared__ float Abuf[64 * 65];
    __shared__ float4 Wbuf[64 * 16];
    int tid = threadIdx.x;
    int i = tid & 15, j = tid >> 4;
    int rowbase = blockIdx.x * 64;
    float4 bv = ((const float4*)brel)[j];
    float acc[4][4];
#pragma unroll
    for (int r = 0; r < 4; r++) { acc[r][0] = bv.x; acc[r][1] = bv.y; acc[r][2] = bv.z; acc[r][3] = bv.w; }

    for (int c0 = 0; c0 < 2 * KIN; c0 += 64) {
        __syncthreads();
        // stage A chunk: 64 rows × 64 k (1024 float4)
        for (int t = tid; t < 1024; t += 256) {
            int r = t >> 4, k4 = t & 15;
            int kg = c0 + 4 * k4;
            int row = rowbase + r; if (row >= N) row = N - 1;
            float4 v;
            if (kg < KIN) {
                v = ((const float4*)(agg + (size_t)row * KIN))[kg >> 2];
            } else {
                int kk = kg - KIN;
                const float* h = (row < split) ? hinA + (size_t)row * KIN
                                               : hinB + (size_t)(row - split) * KIN;
                v = ((const float4*)h)[kk >> 2];
            }
            float* d = Abuf + r * 65 + 4 * k4;
            d[0] = v.x; d[1] = v.y; d[2] = v.z; d[3] = v.w;
        }
        // stage W chunk: 64 k × 16 float4
        for (int t = tid; t < 1024; t += 256) {
            int k = t >> 4, jj = t & 15;
            int kg = c0 + k;
            const float* Wsrc = (kg < KIN) ? (Wrel + (size_t)kg * 64)
                                           : (Wroot + (size_t)(kg - KIN) * 64);
            Wbuf[t] = ((const float4*)Wsrc)[jj];
        }
        __syncthreads();
#pragma unroll 4
        for (int k = 0; k < 64; k++) {
            float4 wv = Wbuf[k * 16 + j];
            float a0 = Abuf[(4 * i + 0) * 65 + k];
            float a1 = Abuf[(4 * i + 1) * 65 + k];
            float a2 = Abuf[(4 * i + 2) * 65 + k];
            float a3 = Abuf[(4 * i + 3) * 65 + k];
            acc[0][0] = fmaf(a0, wv.x, acc[0][0]); acc[0][1] = fmaf(a0, wv.y, acc[0][1]);
            acc[0][2] = fmaf(a0, wv.z, acc[0][2]); acc[0][3] = fmaf(a0, wv.w, acc[0][3]);
            acc[1][0] = fmaf(a1, wv.x, acc[1][0]); acc[1][1] = fmaf(a1, wv.y, acc[1][1]);
            acc[1][2] = fmaf(a1, wv.z, acc[1][2]); acc[1][3] = fmaf(a1, wv.w, acc[1][3]);
            acc[2][0] = fmaf(a2, wv.x, acc[2][0]); acc[2][1] = fmaf(a2, wv.y, acc[2][1]);
            acc[2][2] = fmaf(a2, wv.z, acc[2][2]); acc[2][3] = fmaf(a2, wv.w, acc[2][3]);
            acc[3][0] = fmaf(a3, wv.x, acc[3][0]); acc[3][1] = fmaf(a3, wv.y, acc[3][1]);
            acc[3][2] = fmaf(a3, wv.z, acc[3][2]); acc[3][3] = fmaf(a3, wv.w, acc[3][3]);
        }
    }
#pragma unroll
    for (int r = 0; r < 4; r++) {
        int row = rowbase + 4 * i + r;
        if (row < N) {
            float4 o = make_float4(fmaxf(acc[r][0], 0.f), fmaxf(acc[r][1], 0.f),
                                   fmaxf(acc[r][2], 0.f), fmaxf(acc[r][3], 0.f));
            ((float4*)(hout + (size_t)row * 64))[j] = o;
        }
    }
}

// emb = normalize([x | h1 | h2] @ W_e + b_e)   (K' = 160, chunks 64,64,32)
__global__ __launch_bounds__(256) void emb_gemm_kernel(const float* __restrict__ xA,
    const float* __restrict__ xB, int split,
    const float* __restrict__ h1, const float* __restrict__ h2,
    const float* __restrict__ We, const float* __restrict__ be,
    float* __restrict__ emb, int N) {
    __shared__ float Abuf[64 * 65];
    __shared__ float4 Wbuf[64 * 16];
    int tid = threadIdx.x;
    int i = tid & 15, j = tid >> 4;
    int rowbase = blockIdx.x * 64;
    float4 bv = ((const float4*)be)[j];
    float acc[4][4];
#pragma unroll
    for (int r = 0; r < 4; r++) { acc[r][0] = bv.x; acc[r][1] = bv.y; acc[r][2] = bv.z; acc[r][3] = bv.w; }

    for (int c0 = 0; c0 < 160; c0 += 64) {
        int kw = (160 - c0 < 64) ? (160 - c0) : 64;      // 64,64,32
        int sh = (kw == 64) ? 4 : 3;
        int msk = (1 << sh) - 1;
        __syncthreads();
        for (int t = tid; t < 64 * (kw >> 2); t += 256) {
            int r = t >> sh, k4 = t & msk;
            int kg = c0 + 4 * k4;
            int row = rowbase + r; if (row >= N) row = N - 1;
            float4 v;
            if (kg < 32) {
                const float* x = (row < split) ? xA + (size_t)row * 32
                                               : xB + (size_t)(row - split) * 32;
                v = ((const float4*)x)[kg >> 2];
            } else if (kg < 96) {
                v = ((const float4*)(h1 + (size_t)row * 64))[(kg - 32) >> 2];
            } else {
                v = ((const float4*)(h2 + (size_t)row * 64))[(kg - 96) >> 2];
            }
            float* d = Abuf + r * 65 + 4 * k4;
            d[0] = v.x; d[1] = v.y; d[2] = v.z; d[3] = v.w;
        }
        for (int t = tid; t < kw * 16; t += 256) {
            int k = t >> 4, jj = t & 15;
            Wbuf[t] = ((const float4*)(We + (size_t)(c0 + k) * 64))[jj];
        }
        __syncthreads();
#pragma unroll 4
        for (int k = 0; k < kw; k++) {
            float4 wv = Wbuf[k * 16 + j];
            float a0 = Abuf[(4 * i + 0) * 65 + k];
            float a1 = Abuf[(4 * i + 1) * 65 + k];
            float a2 = Abuf[(4 * i + 2) * 65 + k];
            float a3 = Abuf[(4 * i + 3) * 65 + k];
            acc[0][0] = fmaf(a0, wv.x, acc[0][0]); acc[0][1] = fmaf(a0, wv.y, acc[0][1]);
            acc[0][2] = fmaf(a0, wv.z, acc[0][2]); acc[0][3] = fmaf(a0, wv.w, acc[0][3]);
            acc[1][0] = fmaf(a1, wv.x, acc[1][0]); acc[1][1] = fmaf(a1, wv.y, acc[1][1]);
            acc[1][2] = fmaf(a1, wv.z, acc[1][2]); acc[1][3] = fmaf(a1, wv.w, acc[1][3]);
            acc[2][0] = fmaf(a2, wv.x, acc[2][0]); acc[2][1] = fmaf(a2, wv.y, acc[2][1]);
            acc[2][2] = fmaf(a2, wv.z, acc[2][2]); acc[2][3] = fmaf(a2, wv.w, acc[2][3]);
            acc[3][0] = fmaf(a3, wv.x, acc[3][0]); acc[3][1] = fmaf(a3, wv.y, acc[3][1]);
            acc[3][2] = fmaf(a3, wv.z, acc[3][2]); acc[3][3] = fmaf(a3, wv.w, acc[3][3]);
        }
    }
    // normalize epilogue: park pre-norm rows in Abuf, then wave-per-row reduce
    __syncthreads();
#pragma unroll
    for (int r = 0; r < 4; r++)
#pragma unroll
        for (int c = 0; c < 4; c++)
            Abuf[(4 * i + r) * 65 + 4 * j + c] = acc[r][c];
    __syncthreads();
    int lane = tid & 63, wv = tid >> 6;
    for (int rr = 0; rr < 16; rr++) {
        int r = wv * 16 + rr;
        float val = Abuf[r * 65 + lane];
        float ss = val * val;
#pragma unroll
        for (int d = 32; d > 0; d >>= 1) ss += __shfl_xor(ss, d, 64);
        int row = rowbase + r;
        if (row < N) emb[(size_t)row * 64 + lane] = val / fmaxf(sqrtf(ss), 1e-12f);
    }
}

// ---------------- cost: per (pair, 96-row half), cdist + masking ----------------
__global__ __launch_bounds__(256) void cost_kernel(const float* __restrict__ embS,
                                                   const float* __restrict__ embT,
                                                   const float* __restrict__ vraw,
                                                   const int* __restrict__ lenS,
                                                   const int* __restrict__ lenT,
                                                   const int* __restrict__ off,
                                                   float* __restrict__ cost, int Ns) {
    int p = blockIdx.x >> 1;
    int half = blockIdx.x & 1;
    __shared__ float sS[96 * 65];
    __shared__ float sT[192 * 65];
    __shared__ float sqS[96];
    __shared__ float sqT[192];
    __shared__ __align__(16) float virt[64];
    int tid = threadIdx.x;
    int n = lenS[p], m = lenT[p];
    int offs = off[p], offt = off[PAIRS + p];

    if (tid < 64) {
        float v = vraw[tid];
        float ss = v * v;
#pragma unroll
        for (int d = 32; d > 0; d >>= 1) ss += __shfl_xor(ss, d, 64);
        virt[tid] = v / fmaxf(sqrtf(ss), 1e-12f);
    }
    __syncthreads();

    for (int t = tid; t < 96 * 16; t += 256) {
        int r = t >> 4, q = t & 15;
        int gi = offs + half * 96 + r;
        if (gi > Ns - 1) gi = Ns - 1;
        float4 vv = ((const float4*)embS)[(size_t)gi * 16 + q];
        sS[r * 65 + q * 4 + 0] = vv.x;
        sS[r * 65 + q * 4 + 1] = vv.y;
        sS[r * 65 + q * 4 + 2] = vv.z;
        sS[r * 65 + q * 4 + 3] = vv.w;
    }
    for (int t = tid; t < 192 * 16; t += 256) {
        int j = t >> 4, q = t & 15;
        float4 vv;
        if (j < m) vv = ((const float4*)embT)[(size_t)(offt + j) * 16 + q];
        else       vv = ((const float4*)virt)[q];
        sT[j * 65 + q * 4 + 0] = vv.x;
        sT[j * 65 + q * 4 + 1] = vv.y;
        sT[j * 65 + q * 4 + 2] = vv.z;
        sT[j * 65 + q * 4 + 3] = vv.w;
    }
    __syncthreads();

    for (int r = tid; r < 96; r += 256) {
        float s = 0.f;
#pragma unroll
        for (int k = 0; k < 64; k++) { float a = sS[r * 65 + k]; s = fmaf(a, a, s); }
        sqS[r] = s;
    }
    for (int j = tid; j < 192; j += 256) {
        float s = 0.f;
#pragma unroll
        for (int k = 0; k < 64; k++) { float a = sT[j * 65 + k]; s = fmaf(a, a, s); }
        sqT[j] = s;
    }
    __syncthreads();

    int ti = tid & 15, tj = tid >> 4;
    int ibase = ti * 6, jbase = tj * 12;
    float acc[6][12];
#pragma unroll
    for (int r = 0; r < 6; r++)
#pragma unroll
        for (int c = 0; c < 12; c++) acc[r][c] = 0.f;

    for (int k = 0; k < 64; k++) {
        float sv[6], tv[12];
#pragma unroll
        for (int r = 0; r < 6; r++) sv[r] = sS[(ibase + r) * 65 + k];
#pragma unroll
        for (int c = 0; c < 12; c++) tv[c] = sT[(jbase + c) * 65 + k];
#pragma unroll
        for (int r = 0; r < 6; r++)
#pragma unroll
            for (int c = 0; c < 12; c++) acc[r][c] = fmaf(sv[r], tv[c], acc[r][c]);
    }

    int i0 = half * 96;
#pragma unroll
    for (int r = 0; r < 6; r++) {
        int i = i0 + ibase + r;
        bool rv = i < n;
        float sqi = sqS[ibase + r];
        float* orow = cost + ((size_t)p * MAXN + i) * MAXN + jbase;
        float tmp[12];
#pragma unroll
        for (int c = 0; c < 12; c++) {
            int j = jbase + c;
            float cd = sqrtf(fmaxf(sqi + sqT[j] - 2.f * acc[r][c], 1e-12f));
            bool cv = j < n;
            tmp[c] = (rv && cv) ? cd : ((!rv && !cv) ? 0.f : 1000.f);
        }
#pragma unroll
        for (int q = 0; q < 3; q++)
            ((float4*)orow)[q] = make_float4(tmp[4 * q], tmp[4 * q + 1], tmp[4 * q + 2], tmp[4 * q + 3]);
    }
}

// ---------------- Sinkhorn: 1024 threads, 4-way striped matvec, K in LDS ----------------
__global__ __launch_bounds__(1024) void sinkhorn_kernel(const float* __restrict__ cost,
                                                        float* __restrict__ gamma,
                                                        float* __restrict__ geds2,
                                                        const int* __restrict__ lenS,
                                                        const int* __restrict__ lenT) {
    int p = blockIdx.x;
    __shared__ float K[MAXN * 193];
    __shared__ float part[4 * MAXN];
    __shared__ float u[MAXN];
    __shared__ float v[MAXN];
    __shared__ float wsum[16];
    int tid = threadIdx.x;
    const float* cp = cost + (size_t)p * MAXN * MAXN;

    for (int t = tid; t < MAXN * MAXN; t += 1024) {
        int i = t / MAXN, j = t - i * MAXN;
        K[i * 193 + j] = expf(-10.f * cp[t]);
    }
    if (tid < MAXN) u[tid] = 1.f / 192.f;

    int g = tid >> 8;
    int r = tid & 255;
    int base = g * 48;

    for (int it = 0; it < 8; it++) {
        __syncthreads();
        if (r < MAXN) {
            float s = 0.f;
#pragma unroll
            for (int q = 0; q < 48; q++) { int i = base + q; s = fmaf(K[i * 193 + r], u[i], s); }
            part[g * MAXN + r] = s;
        }
        __syncthreads();
        if (tid < MAXN)
            v[tid] = 1.f / (part[tid] + part[MAXN + tid] + part[2 * MAXN + tid] + part[3 * MAXN + tid]);
        __syncthreads();
        if (r < MAXN) {
            float s = 0.f;
#pragma unroll
            for (int q = 0; q < 48; q++) { int j = base + q; s = fmaf(K[r * 193 + j], v[j], s); }
            part[g * MAXN + r] = s;
        }
        __syncthreads();
        if (tid < MAXN)
            u[tid] = 1.f / (part[tid] + part[MAXN + tid] + part[2 * MAXN + tid] + part[3 * MAXN + tid]);
    }
    __syncthreads();

    float acc = 0.f;
    float* gp = gamma + (size_t)p * MAXN * MAXN;
    for (int t = tid; t < MAXN * MAXN; t += 1024) {
        int i = t / MAXN, j = t - i * MAXN;
        float Kij = K[i * 193 + j];
        float gg = u[i] * Kij * v[j];
        gp[t] = gg;
        if (Kij > 0.f) acc = fmaf(gg, -0.1f * logf(Kij), acc);
    }
#pragma unroll
    for (int d = 32; d > 0; d >>= 1) acc += __shfl_xor(acc, d, 64);
    if ((tid & 63) == 0) wsum[tid >> 6] = acc;
    __syncthreads();
    if (tid == 0) {
        float s = 0.f;
        for (int q = 0; q < 16; q++) s += wsum[q];
        geds2[p] = s / (float)(lenS[p] + lenT[p]);
    }
}

extern "C" void kernel_launch(void* const* d_in, const int* in_sizes, int n_in,
                              void* d_out, int out_size, void* d_ws, size_t ws_size,
                              hipStream_t stream) {
    const float* x_s     = (const float*)d_in[0];
    const float* x_t     = (const float*)d_in[1];
    const float* W_rel0  = (const float*)d_in[2];
    const float* b_rel0  = (const float*)d_in[3];
    const float* W_root0 = (const float*)d_in[4];
    const float* W_rel1  = (const float*)d_in[5];
    const float* b_rel1  = (const float*)d_in[6];
    const float* W_root1 = (const float*)d_in[7];
    const float* W_e     = (const float*)d_in[8];
    const float* b_e     = (const float*)d_in[9];
    const float* virt    = (const float*)d_in[10];
    const int*   ei_s    = (const int*)d_in[11];
    const int*   ei_t    = (const int*)d_in[12];
    const int*   len_s   = (const int*)d_in[13];
    const int*   len_t   = (const int*)d_in[14];

    int Ns = in_sizes[0] / 32;
    int Nt = in_sizes[1] / 32;
    int Es = in_sizes[11] / 2;
    int Et = in_sizes[12] / 2;
    int Ntot = Ns + Nt;
    int Etot = Es + Et;

    // ---- workspace layout ----
    char* w = (char*)d_ws;
    int* off  = (int*)w;              w += 1024 * 4;
    int* bsum = (int*)w;              w += 256 * 4;
    int* rs   = (int*)w;              w += (size_t)Ntot * 4;
    int* cur  = (int*)w;              w += (size_t)Ntot * 4;
    int* src  = (int*)w;              w += (size_t)Etot * 4;
    w = (char*)(((size_t)w + 255) & ~(size_t)255);
    float* agg = (float*)w;           w += (size_t)Ntot * 64 * 4;  // gather out; later emb
    float* h1  = (float*)w;           w += (size_t)Ntot * 64 * 4;
    float* h2  = (float*)w;           w += (size_t)Ntot * 64 * 4;

    float* out_gamma = (float*)d_out;
    float* out_cost  = out_gamma + (size_t)PAIRS * MAXN * MAXN;
    float* out_geds  = out_cost + (size_t)PAIRS * MAXN * MAXN;

    offsets_kernel<<<1, PAIRS, 0, stream>>>(len_s, len_t, off);

    // ---- combined CSR build ----
    hipMemsetAsync(rs, 0, (size_t)Ntot * 4, stream);
    count2_kernel<<<(Etot + 255) / 256, 256, 0, stream>>>(ei_s, ei_t, rs, Es, Et, Ns);
    int nb = (Ntot + 1023) / 1024;
    scan1_kernel<<<nb, 256, 0, stream>>>(rs, bsum, Ntot);
    scan2_kernel<<<1, 256, 0, stream>>>(bsum, nb);
    scan3_kernel<<<(Ntot + 255) / 256, 256, 0, stream>>>(rs, bsum, cur, Ntot);
    fill2_kernel<<<(Etot + 255) / 256, 256, 0, stream>>>(ei_s, ei_t, cur, src, Es, Et, Ns);

    int gblk = (Ntot + 63) / 64;

    // ---- combined GNN ----
    gather_kernel<32><<<(int)(((long long)Ntot * 32 + 255) / 256), 256, 0, stream>>>(
        x_s, x_t, Ns, rs, cur, src, agg, Ntot);
    lin_gemm_kernel<32><<<gblk, 256, 0, stream>>>(
        agg, x_s, x_t, Ns, W_rel0, b_rel0, W_root0, h1, Ntot);
    gather_kernel<64><<<(int)(((long long)Ntot * 64 + 255) / 256), 256, 0, stream>>>(
        h1, h1, Ns, rs, cur, src, agg, Ntot);
    lin_gemm_kernel<64><<<gblk, 256, 0, stream>>>(
        agg, h1, h1, Ntot + 1, W_rel1, b_rel1, W_root1, h2, Ntot);  // h1 combined: split never hit
    emb_gemm_kernel<<<gblk, 256, 0, stream>>>(
        x_s, x_t, Ns, h1, h2, W_e, b_e, agg, Ntot);  // emb -> agg (S rows then T rows)

    // ---- cost + sinkhorn ----
    cost_kernel<<<PAIRS * 2, 256, 0, stream>>>(
        agg, agg + (size_t)Ns * 64, virt, len_s, len_t, off, out_cost, Ns);
    sinkhorn_kernel<<<PAIRS, 1024, 0, stream>>>(out_cost, out_gamma, out_geds, len_s, len_t);
}